// Round 5
// baseline (405.278 us; speedup 1.0000x reference)
//
#include <hip/hip_runtime.h>
#include <math.h>

#define BS   8
#define CIN  512
#define HC_  64
#define C2   256
#define NPIX 4096
#define WAO  384
#define TK   32           // KV tile size in k_attn
#define NT   (NPIX / TK)  // 128 KV steps

typedef __attribute__((ext_vector_type(8))) short short8;
typedef __attribute__((ext_vector_type(4))) float f32x4;

__device__ __forceinline__ ushort f2bf(float f) {
    union { float f; unsigned int u; } v; v.f = f;
    return (ushort)((v.u + 0x7FFFu + ((v.u >> 16) & 1u)) >> 16);
}

#define MFMA16(a, b, c) __builtin_amdgcn_mfma_f32_16x16x32_bf16((a), (b), (c), 0, 0, 0)

// async global->LDS, 16B per lane; LDS dest = base + lane*16 (wave-uniform base)
__device__ __forceinline__ void gl_lds16(const ushort* g, ushort* l) {
    __builtin_amdgcn_global_load_lds(
        (const __attribute__((address_space(1))) unsigned int*)g,
        (__attribute__((address_space(3))) unsigned int*)l, 16, 0, 0);
}

// ---------------------------------------------------------------------------
// Kernel W: convert Wa (384x512) and Wo (512x256) fp32 -> bf16 once.
// ---------------------------------------------------------------------------
__global__ __launch_bounds__(256) void k_cvt_w(
    const float* __restrict__ Wa, const float* __restrict__ Wo,
    ushort* __restrict__ wab, ushort* __restrict__ wob)
{
    const int i = (blockIdx.x * 256 + threadIdx.x) * 4;
    const int na = WAO * CIN;
    if (i < na) {
        const float4 v = *(const float4*)&Wa[i];
        ushort4 o; o.x = f2bf(v.x); o.y = f2bf(v.y); o.z = f2bf(v.z); o.w = f2bf(v.w);
        *(ushort4*)&wab[i] = o;
    } else {
        const int j = i - na;
        if (j < CIN * C2) {
            const float4 v = *(const float4*)&Wo[j];
            ushort4 o; o.x = f2bf(v.x); o.y = f2bf(v.y); o.z = f2bf(v.z); o.w = f2bf(v.w);
            *(ushort4*)&wob[j] = o;
        }
    }
}

// ---------------------------------------------------------------------------
// Kernel A: w = Wa @ inputs (1x1 conv), MFMA bf16.
// Staging: thread owns 8 channels x 1 pixel -> vectorized uint2 LDS writes
// (2-way banks, free) + double-buffered (1 barrier/step).
// Writes qt[b][n][64], kt[b][m][64] (transposed), vb[b][c][m] (natural).
// ---------------------------------------------------------------------------
__global__ __launch_bounds__(256) void k_proj_a(
    const float* __restrict__ inp, const ushort* __restrict__ wab,
    ushort* __restrict__ qt, ushort* __restrict__ kt, ushort* __restrict__ vb)
{
    __shared__ __align__(16) ushort it[2][64][40];
    const int b  = blockIdx.z;
    const int o0 = blockIdx.y * 128;
    const int n0 = blockIdx.x * 64;
    const int t    = threadIdx.x;
    const int wave = t >> 6, lane = t & 63;
    const int ln   = lane & 15, gr = lane >> 4;
    const int wn   = wave * 16;

    f32x4 acc[8];
#pragma unroll
    for (int i = 0; i < 8; ++i) acc[i] = (f32x4){0.f, 0.f, 0.f, 0.f};

    const int sn = t & 63;           // pixel within tile
    const int cw = (t >> 6) * 8;     // this thread's 8-channel group

    auto stage = [&](int buf, int ks) {
        const int c0 = ks * 32;
        float x[8];
#pragma unroll
        for (int j = 0; j < 8; ++j)
            x[j] = inp[((size_t)b * CIN + c0 + cw + j) * NPIX + n0 + sn];
        uint2 w0, w1;
        w0.x = (unsigned int)f2bf(x[0]) | ((unsigned int)f2bf(x[1]) << 16);
        w0.y = (unsigned int)f2bf(x[2]) | ((unsigned int)f2bf(x[3]) << 16);
        w1.x = (unsigned int)f2bf(x[4]) | ((unsigned int)f2bf(x[5]) << 16);
        w1.y = (unsigned int)f2bf(x[6]) | ((unsigned int)f2bf(x[7]) << 16);
        *(uint2*)&it[buf][sn][cw]     = w0;
        *(uint2*)&it[buf][sn][cw + 4] = w1;
    };

    stage(0, 0);
    for (int ks = 0; ks < 16; ++ks) {
        __syncthreads();
        if (ks < 15) stage((ks + 1) & 1, ks + 1);
        const int c0 = ks * 32;
        const short8 bf = *(const short8*)&it[ks & 1][wn + ln][gr * 8];
#pragma unroll
        for (int ot = 0; ot < 8; ++ot) {
            const int row = o0 + ot * 16 + ln;
            const short8 af = *(const short8*)&wab[(size_t)row * CIN + c0 + gr * 8];
            acc[ot] = MFMA16(af, bf, acc[ot]);
        }
    }

    const int n = n0 + wn + ln;
    if (o0 == 0) {
#pragma unroll
        for (int ot = 0; ot < 8; ++ot) {
            const ushort b0 = f2bf(acc[ot][0]), b1 = f2bf(acc[ot][1]);
            const ushort b2 = f2bf(acc[ot][2]), b3 = f2bf(acc[ot][3]);
            uint2 pk;
            pk.x = (unsigned int)b0 | ((unsigned int)b1 << 16);
            pk.y = (unsigned int)b2 | ((unsigned int)b3 << 16);
            ushort* base = (ot < 4) ? qt : kt;
            const int c4 = (ot & 3) * 16 + 4 * gr;
            *(uint2*)&base[((size_t)b * NPIX + n) * 64 + c4] = pk;
        }
    } else {
#pragma unroll
        for (int ot = 0; ot < 8; ++ot) {
            const int cb = o0 - 128 + ot * 16 + 4 * gr;
#pragma unroll
            for (int r = 0; r < 4; ++r)
                vb[((size_t)b * C2 + cb + r) * NPIX + n] = f2bf(acc[ot][r]);
        }
    }
}

// ---------------------------------------------------------------------------
// Kernel B: flash attention, bf16 MFMA. Wave = 32 q-rows (2 row-groups reuse
// each V fragment -> halves V LDS-read bytes per row, the measured
// bottleneck). Block = 2 waves = 64 rows; grid 512, b = bid&7 (XCD/L2).
// K ring-3 + V ring-2 staging, steady-state s_waitcnt vmcnt(2), never 0.
// LDS: K 12K + V 32K + P 5K = 49 KB.
// ---------------------------------------------------------------------------
__global__ __launch_bounds__(128, 2) void k_attn(
    const ushort* __restrict__ qt, const ushort* __restrict__ kt,
    const ushort* __restrict__ vb, ushort* __restrict__ yt)
{
    __shared__ __align__(16) ushort ks[3][TK][64];    // [m][c], slot ^= (m&7)
    __shared__ __align__(16) ushort vs[2][C2][TK];    // [c][m], slot ^= ((c>>1)&3)
    __shared__ __align__(16) ushort ps[2][32][40];    // per-wave P [n32][m]

    const int bid = blockIdx.x;
    const int b   = bid & 7;
    const int n0  = (bid >> 3) * 64;
    const int t    = threadIdx.x;
    const int wave = t >> 6, lane = t & 63;
    const int ln   = lane & 15, gr = lane >> 4;

    const ushort* ktb = kt + (size_t)b * NPIX * 64;
    const ushort* vbb = vb + (size_t)b * C2 * NPIX;

    // Q fragments for the wave's two 16-row groups
    short8 qf[2][2];
#pragma unroll
    for (int rg = 0; rg < 2; ++rg) {
        const int qrow = n0 + wave * 32 + rg * 16 + ln;
        qf[rg][0] = *(const short8*)&qt[((size_t)b * NPIX + qrow) * 64 + gr * 8];
        qf[rg][1] = *(const short8*)&qt[((size_t)b * NPIX + qrow) * 64 + 32 + gr * 8];
    }
    asm volatile("s_waitcnt vmcnt(0)" ::: "memory");   // exact vmcnt accounting
    __builtin_amdgcn_sched_barrier(0);

    // swizzled read offsets (ushort units)
    const int ksl0 = ((gr ^ (ln & 7)) << 3);
    const int ksl1 = (((4 + gr) ^ (ln & 7)) << 3);
    const int vsl  = ((gr ^ ((ln >> 1) & 3)) << 3);
    // staging lane roles (source pre-swizzled; LDS dest linear)
    const int krow = lane >> 3, kslot = (lane & 7) ^ krow;     // 8 rows/instr
    const int vrow = lane >> 2, vslot = (lane & 3) ^ ((lane >> 3) & 3); // 16 rows/instr

    auto stage_k = [&](int buf, int tile) {
        const int m0 = tile * TK;
#pragma unroll
        for (int jj = 0; jj < 2; ++jj) {
            const int r0 = 16 * wave + 8 * jj;
            gl_lds16(&ktb[(size_t)(m0 + r0 + krow) * 64 + kslot * 8],
                     &ks[buf][r0][0]);
        }
    };
    auto stage_v = [&](int buf, int tile) {
        const int m0 = tile * TK;
#pragma unroll
        for (int jj = 0; jj < 8; ++jj) {
            const int r0 = 128 * wave + 16 * jj;
            gl_lds16(&vbb[(size_t)(r0 + vrow) * NPIX + m0 + vslot * 8],
                     &vs[buf][r0][0]);
        }
    };

    f32x4 yacc[16][2];
#pragma unroll
    for (int i = 0; i < 16; ++i)
#pragma unroll
        for (int rg = 0; rg < 2; ++rg) yacc[i][rg] = (f32x4){0.f, 0.f, 0.f, 0.f};
    float mrun[2] = {-INFINITY, -INFINITY};
    float lrun[2] = {0.f, 0.f};
    const f32x4 zero = {0.f, 0.f, 0.f, 0.f};

    stage_k(0, 0);
    stage_v(0, 0);
    stage_k(1, 1);
    asm volatile("s_waitcnt vmcnt(2)" ::: "memory");
    __builtin_amdgcn_s_barrier();
    __builtin_amdgcn_sched_barrier(0);

    int kcur = 0, vcur = 0;
    for (int tt = 0; tt < NT; ++tt) {
        if (tt + 1 < NT) stage_v(vcur ^ 1, tt + 1);
        if (tt + 2 < NT) { int kp = kcur + 2; if (kp >= 3) kp -= 3; stage_k(kp, tt + 2); }

        // ---- S^T = K Q for both row groups (K frags shared) ----
        const ushort* kb = &ks[kcur][0][0];
        f32x4 s[2][2];
#pragma unroll
        for (int mt = 0; mt < 2; ++mt) {
            const ushort* kp = kb + (mt * 16 + ln) * 64;
            const short8 kf0 = *(const short8*)(kp + ksl0);
            const short8 kf1 = *(const short8*)(kp + ksl1);
#pragma unroll
            for (int rg = 0; rg < 2; ++rg)
                s[mt][rg] = MFMA16(kf1, qf[rg][1], MFMA16(kf0, qf[rg][0], zero));
        }
        // ---- online softmax per row group, defer-max (THR=8) ----
#pragma unroll
        for (int rg = 0; rg < 2; ++rg) {
            float tm = fmaxf(
                fmaxf(fmaxf(s[0][rg][0], s[0][rg][1]), fmaxf(s[0][rg][2], s[0][rg][3])),
                fmaxf(fmaxf(s[1][rg][0], s[1][rg][1]), fmaxf(s[1][rg][2], s[1][rg][3])));
            tm = fmaxf(tm, __shfl_xor(tm, 16));
            tm = fmaxf(tm, __shfl_xor(tm, 32));
            if (__any(tm > mrun[rg] + 8.f)) {
                const float mnew = fmaxf(mrun[rg], tm);
                const float rsc  = __expf(mrun[rg] - mnew);
                mrun[rg] = mnew;
                lrun[rg] *= rsc;
                const float r0 = __shfl(rsc, 4 * gr + 0);
                const float r1 = __shfl(rsc, 4 * gr + 1);
                const float r2 = __shfl(rsc, 4 * gr + 2);
                const float r3 = __shfl(rsc, 4 * gr + 3);
#pragma unroll
                for (int ct = 0; ct < 16; ++ct) {
                    yacc[ct][rg][0] *= r0; yacc[ct][rg][1] *= r1;
                    yacc[ct][rg][2] *= r2; yacc[ct][rg][3] *= r3;
                }
            }
            const float p0 = __expf(s[0][rg][0] - mrun[rg]);
            const float p1 = __expf(s[0][rg][1] - mrun[rg]);
            const float p2 = __expf(s[0][rg][2] - mrun[rg]);
            const float p3 = __expf(s[0][rg][3] - mrun[rg]);
            const float p4 = __expf(s[1][rg][0] - mrun[rg]);
            const float p5 = __expf(s[1][rg][1] - mrun[rg]);
            const float p6 = __expf(s[1][rg][2] - mrun[rg]);
            const float p7 = __expf(s[1][rg][3] - mrun[rg]);
            uint2 w0, w1;
            w0.x = (unsigned int)f2bf(p0) | ((unsigned int)f2bf(p1) << 16);
            w0.y = (unsigned int)f2bf(p2) | ((unsigned int)f2bf(p3) << 16);
            w1.x = (unsigned int)f2bf(p4) | ((unsigned int)f2bf(p5) << 16);
            w1.y = (unsigned int)f2bf(p6) | ((unsigned int)f2bf(p7) << 16);
            *(uint2*)&ps[wave][rg * 16 + ln][4 * gr]      = w0;
            *(uint2*)&ps[wave][rg * 16 + ln][16 + 4 * gr] = w1;
            float rsum = (p0 + p1) + (p2 + p3) + ((p4 + p5) + (p6 + p7));
            rsum += __shfl_xor(rsum, 16);
            rsum += __shfl_xor(rsum, 32);
            lrun[rg] += rsum;
        }
        asm volatile("s_waitcnt lgkmcnt(0)" ::: "memory");   // P writes visible
        __builtin_amdgcn_sched_barrier(0);
        short8 pf[2];
        pf[0] = *(const short8*)&ps[wave][ln][gr * 8];
        pf[1] = *(const short8*)&ps[wave][16 + ln][gr * 8];
        // ---- Y += P V^T : each vf fragment reused by both row groups ----
        const ushort* vbase = &vs[vcur][0][0];
        __builtin_amdgcn_s_setprio(1);
#pragma unroll
        for (int ct = 0; ct < 16; ++ct) {
            const short8 vf = *(const short8*)(vbase + (ct * 16 + ln) * TK + vsl);
            yacc[ct][0] = MFMA16(pf[0], vf, yacc[ct][0]);
            yacc[ct][1] = MFMA16(pf[1], vf, yacc[ct][1]);
        }
        __builtin_amdgcn_s_setprio(0);
        __builtin_amdgcn_sched_barrier(0);
        if (tt + 1 < NT) {
            if (tt + 2 < NT) { asm volatile("s_waitcnt vmcnt(2)" ::: "memory"); }
            else             { asm volatile("s_waitcnt vmcnt(0)" ::: "memory"); }
            __builtin_amdgcn_s_barrier();
            __builtin_amdgcn_sched_barrier(0);
        }
        kcur = kcur + 1; if (kcur >= 3) kcur -= 3;
        vcur ^= 1;
    }

#pragma unroll
    for (int rg = 0; rg < 2; ++rg) {
        const float il0 = 1.f / __shfl(lrun[rg], 4 * gr + 0);
        const float il1 = 1.f / __shfl(lrun[rg], 4 * gr + 1);
        const float il2 = 1.f / __shfl(lrun[rg], 4 * gr + 2);
        const float il3 = 1.f / __shfl(lrun[rg], 4 * gr + 3);
        const int nb = n0 + wave * 32 + rg * 16 + 4 * gr;
#pragma unroll
        for (int ct = 0; ct < 16; ++ct) {
            const int c = ct * 16 + ln;
            yt[((size_t)b * NPIX + nb + 0) * C2 + c] = f2bf(yacc[ct][rg][0] * il0);
            yt[((size_t)b * NPIX + nb + 1) * C2 + c] = f2bf(yacc[ct][rg][1] * il1);
            yt[((size_t)b * NPIX + nb + 2) * C2 + c] = f2bf(yacc[ct][rg][2] * il2);
            yt[((size_t)b * NPIX + nb + 3) * C2 + c] = f2bf(yacc[ct][rg][3] * il3);
        }
    }
}

// ---------------------------------------------------------------------------
// Kernel C: out = gamma * (Wo @ y) + inputs, MFMA bf16, no LDS.
// ---------------------------------------------------------------------------
__global__ __launch_bounds__(256) void k_proj_o(
    const ushort* __restrict__ yt, const ushort* __restrict__ wob,
    const float* __restrict__ inp, const float* __restrict__ gamma,
    float* __restrict__ out)
{
    const int b  = blockIdx.z;
    const int j0 = blockIdx.y * 128;
    const int n0 = blockIdx.x * 64;
    const int t    = threadIdx.x;
    const int wave = t >> 6, lane = t & 63;
    const int ln   = lane & 15, gr = lane >> 4;
    const int n = n0 + wave * 16 + ln;

    f32x4 acc[8];
#pragma unroll
    for (int i = 0; i < 8; ++i) acc[i] = (f32x4){0.f, 0.f, 0.f, 0.f};

#pragma unroll
    for (int ksi = 0; ksi < 8; ++ksi) {
        const int c0 = ksi * 32;
        const short8 bf = *(const short8*)&yt[((size_t)b * NPIX + n) * C2 + c0 + gr * 8];
#pragma unroll
        for (int jt = 0; jt < 8; ++jt) {
            const int row = j0 + jt * 16 + ln;
            const short8 af = *(const short8*)&wob[(size_t)row * C2 + c0 + gr * 8];
            acc[jt] = MFMA16(af, bf, acc[jt]);
        }
    }
    const float g = gamma[0];
#pragma unroll
    for (int jt = 0; jt < 8; ++jt) {
#pragma unroll
        for (int r = 0; r < 4; ++r) {
            const int j = j0 + jt * 16 + 4 * gr + r;
            const size_t idx = ((size_t)b * CIN + j) * NPIX + n;
            out[idx] = fmaf(g, acc[jt][r], inp[idx]);
        }
    }
}

extern "C" void kernel_launch(void* const* d_in, const int* in_sizes, int n_in,
                              void* d_out, int out_size, void* d_ws, size_t ws_size,
                              hipStream_t stream) {
    const float* inputs = (const float*)d_in[0];
    const float* Wa     = (const float*)d_in[1];
    const float* Wo     = (const float*)d_in[2];
    const float* gamma  = (const float*)d_in[3];
    float* out = (float*)d_out;

    const size_t qt_e  = (size_t)BS * NPIX * 64;
    const size_t kt_e  = (size_t)BS * NPIX * 64;
    const size_t vb_e  = (size_t)BS * C2 * NPIX;
    const size_t yt_e  = (size_t)BS * NPIX * C2;
    const size_t wab_e = (size_t)WAO * CIN;
    const size_t wob_e = (size_t)CIN * C2;

    ushort *qt, *kt, *vb, *yt, *wab, *wob;
    if (ws_size >= (qt_e + kt_e + vb_e + yt_e + wab_e + wob_e) * sizeof(ushort)) {
        qt  = (ushort*)d_ws;
        kt  = qt + qt_e;
        vb  = kt + kt_e;
        yt  = vb + vb_e;
        wab = yt + yt_e;
        wob = wab + wab_e;
    } else {
        vb  = (ushort*)d_out;
        qt  = (ushort*)d_ws;
        kt  = qt + qt_e;
        yt  = kt + kt_e;
        wab = yt + yt_e;
        wob = wab + wab_e;
    }

    k_cvt_w <<<dim3(320),      256, 0, stream>>>(Wa, Wo, wab, wob);
    k_proj_a<<<dim3(64, 3, 8), 256, 0, stream>>>(inputs, wab, qt, kt, vb);
    k_attn  <<<dim3(512),      128, 0, stream>>>(qt, kt, vb, yt);
    k_proj_o<<<dim3(64, 4, 8), 256, 0, stream>>>(yt, wob, inputs, gamma, out);
}

// Round 6
// 372.990 us; speedup vs baseline: 1.0866x; 1.0866x over previous
//
#include <hip/hip_runtime.h>
#include <math.h>

#define BS   8
#define CIN  512
#define HC_  64
#define C2   256
#define NPIX 4096
#define WAO  384
#define TK   32           // KV tile size in k_attn
#define NT   (NPIX / TK)  // 128 KV steps

typedef __attribute__((ext_vector_type(8))) short short8;
typedef __attribute__((ext_vector_type(4))) float f32x4;

__device__ __forceinline__ ushort f2bf(float f) {
    union { float f; unsigned int u; } v; v.f = f;
    return (ushort)((v.u + 0x7FFFu + ((v.u >> 16) & 1u)) >> 16);
}

#define MFMA16(a, b, c) __builtin_amdgcn_mfma_f32_16x16x32_bf16((a), (b), (c), 0, 0, 0)

// async global->LDS, 16B per lane; LDS dest = base + lane*16 (wave-uniform base)
__device__ __forceinline__ void gl_lds16(const ushort* g, ushort* l) {
    __builtin_amdgcn_global_load_lds(
        (const __attribute__((address_space(1))) unsigned int*)g,
        (__attribute__((address_space(3))) unsigned int*)l, 16, 0, 0);
}

// ---------------------------------------------------------------------------
// Kernel W: convert Wa (384x512) and Wo (512x256) fp32 -> bf16 once.
// ---------------------------------------------------------------------------
__global__ __launch_bounds__(256) void k_cvt_w(
    const float* __restrict__ Wa, const float* __restrict__ Wo,
    ushort* __restrict__ wab, ushort* __restrict__ wob)
{
    const int i = (blockIdx.x * 256 + threadIdx.x) * 4;
    const int na = WAO * CIN;
    if (i < na) {
        const float4 v = *(const float4*)&Wa[i];
        ushort4 o; o.x = f2bf(v.x); o.y = f2bf(v.y); o.z = f2bf(v.z); o.w = f2bf(v.w);
        *(ushort4*)&wab[i] = o;
    } else {
        const int j = i - na;
        if (j < CIN * C2) {
            const float4 v = *(const float4*)&Wo[j];
            ushort4 o; o.x = f2bf(v.x); o.y = f2bf(v.y); o.z = f2bf(v.z); o.w = f2bf(v.w);
            *(ushort4*)&wob[j] = o;
        }
    }
}

// ---------------------------------------------------------------------------
// Kernel A: w = Wa @ inputs (1x1 conv), MFMA bf16.
// Writes qt[b][n][64], kt[b][m][64] (transposed), vb[b][c][m] (natural).
// ---------------------------------------------------------------------------
__global__ __launch_bounds__(256) void k_proj_a(
    const float* __restrict__ inp, const ushort* __restrict__ wab,
    ushort* __restrict__ qt, ushort* __restrict__ kt, ushort* __restrict__ vb)
{
    __shared__ __align__(16) ushort it[2][64][40];
    const int b  = blockIdx.z;
    const int o0 = blockIdx.y * 128;
    const int n0 = blockIdx.x * 64;
    const int t    = threadIdx.x;
    const int wave = t >> 6, lane = t & 63;
    const int ln   = lane & 15, gr = lane >> 4;
    const int wn   = wave * 16;

    f32x4 acc[8];
#pragma unroll
    for (int i = 0; i < 8; ++i) acc[i] = (f32x4){0.f, 0.f, 0.f, 0.f};

    const int sn = t & 63;           // pixel within tile
    const int cw = (t >> 6) * 8;     // this thread's 8-channel group

    auto stage = [&](int buf, int ks) {
        const int c0 = ks * 32;
        float x[8];
#pragma unroll
        for (int j = 0; j < 8; ++j)
            x[j] = inp[((size_t)b * CIN + c0 + cw + j) * NPIX + n0 + sn];
        uint2 w0, w1;
        w0.x = (unsigned int)f2bf(x[0]) | ((unsigned int)f2bf(x[1]) << 16);
        w0.y = (unsigned int)f2bf(x[2]) | ((unsigned int)f2bf(x[3]) << 16);
        w1.x = (unsigned int)f2bf(x[4]) | ((unsigned int)f2bf(x[5]) << 16);
        w1.y = (unsigned int)f2bf(x[6]) | ((unsigned int)f2bf(x[7]) << 16);
        *(uint2*)&it[buf][sn][cw]     = w0;
        *(uint2*)&it[buf][sn][cw + 4] = w1;
    };

    stage(0, 0);
    for (int ks = 0; ks < 16; ++ks) {
        __syncthreads();
        if (ks < 15) stage((ks + 1) & 1, ks + 1);
        const int c0 = ks * 32;
        const short8 bf = *(const short8*)&it[ks & 1][wn + ln][gr * 8];
#pragma unroll
        for (int ot = 0; ot < 8; ++ot) {
            const int row = o0 + ot * 16 + ln;
            const short8 af = *(const short8*)&wab[(size_t)row * CIN + c0 + gr * 8];
            acc[ot] = MFMA16(af, bf, acc[ot]);
        }
    }

    const int n = n0 + wn + ln;
    if (o0 == 0) {
#pragma unroll
        for (int ot = 0; ot < 8; ++ot) {
            const ushort b0 = f2bf(acc[ot][0]), b1 = f2bf(acc[ot][1]);
            const ushort b2 = f2bf(acc[ot][2]), b3 = f2bf(acc[ot][3]);
            uint2 pk;
            pk.x = (unsigned int)b0 | ((unsigned int)b1 << 16);
            pk.y = (unsigned int)b2 | ((unsigned int)b3 << 16);
            ushort* base = (ot < 4) ? qt : kt;
            const int c4 = (ot & 3) * 16 + 4 * gr;
            *(uint2*)&base[((size_t)b * NPIX + n) * 64 + c4] = pk;
        }
    } else {
#pragma unroll
        for (int ot = 0; ot < 8; ++ot) {
            const int cb = o0 - 128 + ot * 16 + 4 * gr;
#pragma unroll
            for (int r = 0; r < 4; ++r)
                vb[((size_t)b * C2 + cb + r) * NPIX + n] = f2bf(acc[ot][r]);
        }
    }
}

// ---------------------------------------------------------------------------
// Kernel B: flash attention, bf16 MFMA, block-shared P.
// Block = 4 waves x 16 q-rows = 64 rows; grid 512, b = bid&7 (one batch per
// XCD L2). Per step: each wave does QK^T+softmax for its 16 rows -> shared
// P[64][40] -> barrier A -> each wave does PV for ALL 64 rows x its 64-col
// c-quarter (V fragment reused by 4 row-tiles: 44% fewer LDS-read bytes).
// K,V ring-3 staged via global_load_lds; end-of-step s_waitcnt vmcnt(5).
// Defer-max rescale broadcast via LDS resc[64] + per-wave flags.
// LDS: K 12K + V 48K + P 5K + stats ~0.6K = 65.7 KB -> 2 blocks/CU.
// ---------------------------------------------------------------------------
__global__ __launch_bounds__(256, 2) void k_attn(
    const ushort* __restrict__ qt, const ushort* __restrict__ kt,
    const ushort* __restrict__ vb, ushort* __restrict__ yt)
{
    __shared__ __align__(16) ushort ks[3][TK][64];    // [m][c], slot ^= (m&7)
    __shared__ __align__(16) ushort vs[3][C2][TK];    // [c][m], slot ^= ((c>>1)&3)
    __shared__ __align__(16) ushort ps[64][40];       // shared P [q][m], stride 80B
    __shared__ float resc_s[64];
    __shared__ float lsum_s[64];
    __shared__ int   fl[4];

    const int bid = blockIdx.x;
    const int b   = bid & 7;
    const int n0  = (bid >> 3) * 64;
    const int t    = threadIdx.x;
    const int wave = t >> 6, lane = t & 63;
    const int ln   = lane & 15, gr = lane >> 4;

    const ushort* ktb = kt + (size_t)b * NPIX * 64;
    const ushort* vbb = vb + (size_t)b * C2 * NPIX;

    // Q fragments for this wave's 16 rows
    const int qrow = n0 + wave * 16 + ln;
    const short8 qf0 = *(const short8*)&qt[((size_t)b * NPIX + qrow) * 64 + gr * 8];
    const short8 qf1 = *(const short8*)&qt[((size_t)b * NPIX + qrow) * 64 + 32 + gr * 8];
    asm volatile("s_waitcnt vmcnt(0)" ::: "memory");   // exact vmcnt accounting
    __builtin_amdgcn_sched_barrier(0);

    // swizzled read offsets (ushort units)
    const int ksl0 = ((gr ^ (ln & 7)) << 3);
    const int ksl1 = (((4 + gr) ^ (ln & 7)) << 3);
    const int vsl  = ((gr ^ ((ln >> 1) & 3)) << 3);
    // staging lane roles (source pre-swizzled; LDS dest linear)
    const int krow = lane >> 3, kslot = (lane & 7) ^ krow;              // 8 m-rows
    const int vrow = lane >> 2, vslot = (lane & 3) ^ ((vrow >> 1) & 3); // 16 c-rows

    auto stage = [&](int buf, int tile) {
        const int m0 = tile * TK;
#pragma unroll
        for (int jj = 0; jj < 4; ++jj) {
            const int r0 = 64 * wave + 16 * jj;
            gl_lds16(&vbb[(size_t)(r0 + vrow) * NPIX + m0 + vslot * 8],
                     &vs[buf][r0][0]);
        }
        gl_lds16(&ktb[(size_t)(m0 + 8 * wave + krow) * 64 + kslot * 8],
                 &ks[buf][8 * wave][0]);
    };

    f32x4 yacc[4][4];   // [row-tile][c-tile in quarter]
#pragma unroll
    for (int i = 0; i < 4; ++i)
#pragma unroll
        for (int j = 0; j < 4; ++j) yacc[i][j] = (f32x4){0.f, 0.f, 0.f, 0.f};
    float mrun = -INFINITY, lrun = 0.f;
    const f32x4 zero = {0.f, 0.f, 0.f, 0.f};

    stage(0, 0);
    stage(1, 1);
    asm volatile("s_waitcnt vmcnt(5)" ::: "memory");
    __builtin_amdgcn_s_barrier();
    __builtin_amdgcn_sched_barrier(0);

    int cur = 0;
    for (int tt = 0; tt < NT; ++tt) {
        if (tt + 2 < NT) { int pre = cur + 2; if (pre >= 3) pre -= 3; stage(pre, tt + 2); }

        // ---- S^T = K Q : lane holds S[m = mt*16+4gr+r][q = wave*16+ln] ----
        const ushort* kb = &ks[cur][0][0];
        f32x4 s[2];
#pragma unroll
        for (int mt = 0; mt < 2; ++mt) {
            const ushort* kp = kb + (mt * 16 + ln) * 64;
            const short8 kf0 = *(const short8*)(kp + ksl0);
            const short8 kf1 = *(const short8*)(kp + ksl1);
            s[mt] = MFMA16(kf1, qf1, MFMA16(kf0, qf0, zero));
        }
        // ---- online softmax (this wave's 16 rows), defer-max THR=8 ----
        float tm = fmaxf(fmaxf(fmaxf(s[0][0], s[0][1]), fmaxf(s[0][2], s[0][3])),
                         fmaxf(fmaxf(s[1][0], s[1][1]), fmaxf(s[1][2], s[1][3])));
        tm = fmaxf(tm, __shfl_xor(tm, 16));
        tm = fmaxf(tm, __shfl_xor(tm, 32));
        float rsc = 1.f;
        int flag = 0;
        if (__any(tm > mrun + 8.f)) {
            const float mnew = fmaxf(mrun, tm);
            rsc  = __expf(mrun - mnew);
            mrun = mnew;
            lrun *= rsc;
            flag = 1;
        }
        if (lane == 0) fl[wave] = flag;
        if (gr == 0) resc_s[wave * 16 + ln] = rsc;
        const float p0 = __expf(s[0][0] - mrun), p1 = __expf(s[0][1] - mrun);
        const float p2 = __expf(s[0][2] - mrun), p3 = __expf(s[0][3] - mrun);
        const float p4 = __expf(s[1][0] - mrun), p5 = __expf(s[1][1] - mrun);
        const float p6 = __expf(s[1][2] - mrun), p7 = __expf(s[1][3] - mrun);
        uint2 w0, w1;
        w0.x = (unsigned int)f2bf(p0) | ((unsigned int)f2bf(p1) << 16);
        w0.y = (unsigned int)f2bf(p2) | ((unsigned int)f2bf(p3) << 16);
        w1.x = (unsigned int)f2bf(p4) | ((unsigned int)f2bf(p5) << 16);
        w1.y = (unsigned int)f2bf(p6) | ((unsigned int)f2bf(p7) << 16);
        *(uint2*)&ps[wave * 16 + ln][4 * gr]      = w0;
        *(uint2*)&ps[wave * 16 + ln][16 + 4 * gr] = w1;
        float rsum = (p0 + p1) + (p2 + p3) + ((p4 + p5) + (p6 + p7));
        rsum += __shfl_xor(rsum, 16);
        rsum += __shfl_xor(rsum, 32);
        lrun += rsum;

        asm volatile("s_waitcnt lgkmcnt(0)" ::: "memory");   // P/resc/fl visible
        __builtin_amdgcn_sched_barrier(0);
        __builtin_amdgcn_s_barrier();                        // barrier A
        __builtin_amdgcn_sched_barrier(0);

        // ---- apply deferred rescale for any row-tile that renormalized ----
#pragma unroll
        for (int rt = 0; rt < 4; ++rt) {
            if (fl[rt]) {
                const float4 rs = *(const float4*)&resc_s[rt * 16 + 4 * gr];
#pragma unroll
                for (int ct = 0; ct < 4; ++ct) {
                    yacc[rt][ct][0] *= rs.x; yacc[rt][ct][1] *= rs.y;
                    yacc[rt][ct][2] *= rs.z; yacc[rt][ct][3] *= rs.w;
                }
            }
        }
        // ---- PV: all 64 rows x this wave's 64-col c-quarter ----
        short8 pa[4];
#pragma unroll
        for (int rt = 0; rt < 4; ++rt)
            pa[rt] = *(const short8*)&ps[rt * 16 + ln][gr * 8];
        const ushort* vbase = &vs[cur][wave * 64][0];
        __builtin_amdgcn_s_setprio(1);
#pragma unroll
        for (int ct = 0; ct < 4; ++ct) {
            const short8 vf = *(const short8*)(vbase + (ct * 16 + ln) * TK + vsl);
#pragma unroll
            for (int rt = 0; rt < 4; ++rt)
                yacc[rt][ct] = MFMA16(pa[rt], vf, yacc[rt][ct]);
        }
        __builtin_amdgcn_s_setprio(0);
        __builtin_amdgcn_sched_barrier(0);

        if (tt + 1 < NT) {
            if (tt + 2 < NT) { asm volatile("s_waitcnt vmcnt(5)" ::: "memory"); }
            else             { asm volatile("s_waitcnt vmcnt(0)" ::: "memory"); }
            __builtin_amdgcn_s_barrier();                    // barrier B
            __builtin_amdgcn_sched_barrier(0);
        }
        cur = cur + 1; if (cur >= 3) cur -= 3;
    }

    // ---- epilogue: exchange l, normalize, write yt[b][n][c] bf16 ----
    if (gr == 0) lsum_s[wave * 16 + ln] = lrun;
    __syncthreads();
#pragma unroll
    for (int rt = 0; rt < 4; ++rt) {
        const float4 ls = *(const float4*)&lsum_s[rt * 16 + 4 * gr];
        const float i0 = 1.f / ls.x, i1 = 1.f / ls.y;
        const float i2 = 1.f / ls.z, i3 = 1.f / ls.w;
        const int nb = n0 + rt * 16 + 4 * gr;
#pragma unroll
        for (int ct = 0; ct < 4; ++ct) {
            const int c = wave * 64 + ct * 16 + ln;
            yt[((size_t)b * NPIX + nb + 0) * C2 + c] = f2bf(yacc[rt][ct][0] * i0);
            yt[((size_t)b * NPIX + nb + 1) * C2 + c] = f2bf(yacc[rt][ct][1] * i1);
            yt[((size_t)b * NPIX + nb + 2) * C2 + c] = f2bf(yacc[rt][ct][2] * i2);
            yt[((size_t)b * NPIX + nb + 3) * C2 + c] = f2bf(yacc[rt][ct][3] * i3);
        }
    }
}

// ---------------------------------------------------------------------------
// Kernel C: out = gamma * (Wo @ y) + inputs, MFMA bf16, no LDS.
// ---------------------------------------------------------------------------
__global__ __launch_bounds__(256) void k_proj_o(
    const ushort* __restrict__ yt, const ushort* __restrict__ wob,
    const float* __restrict__ inp, const float* __restrict__ gamma,
    float* __restrict__ out)
{
    const int b  = blockIdx.z;
    const int j0 = blockIdx.y * 128;
    const int n0 = blockIdx.x * 64;
    const int t    = threadIdx.x;
    const int wave = t >> 6, lane = t & 63;
    const int ln   = lane & 15, gr = lane >> 4;
    const int n = n0 + wave * 16 + ln;

    f32x4 acc[8];
#pragma unroll
    for (int i = 0; i < 8; ++i) acc[i] = (f32x4){0.f, 0.f, 0.f, 0.f};

#pragma unroll
    for (int ksi = 0; ksi < 8; ++ksi) {
        const int c0 = ksi * 32;
        const short8 bf = *(const short8*)&yt[((size_t)b * NPIX + n) * C2 + c0 + gr * 8];
#pragma unroll
        for (int jt = 0; jt < 8; ++jt) {
            const int row = j0 + jt * 16 + ln;
            const short8 af = *(const short8*)&wob[(size_t)row * C2 + c0 + gr * 8];
            acc[jt] = MFMA16(af, bf, acc[jt]);
        }
    }
    const float g = gamma[0];
#pragma unroll
    for (int jt = 0; jt < 8; ++jt) {
#pragma unroll
        for (int r = 0; r < 4; ++r) {
            const int j = j0 + jt * 16 + 4 * gr + r;
            const size_t idx = ((size_t)b * CIN + j) * NPIX + n;
            out[idx] = fmaf(g, acc[jt][r], inp[idx]);
        }
    }
}

extern "C" void kernel_launch(void* const* d_in, const int* in_sizes, int n_in,
                              void* d_out, int out_size, void* d_ws, size_t ws_size,
                              hipStream_t stream) {
    const float* inputs = (const float*)d_in[0];
    const float* Wa     = (const float*)d_in[1];
    const float* Wo     = (const float*)d_in[2];
    const float* gamma  = (const float*)d_in[3];
    float* out = (float*)d_out;

    const size_t qt_e  = (size_t)BS * NPIX * 64;
    const size_t kt_e  = (size_t)BS * NPIX * 64;
    const size_t vb_e  = (size_t)BS * C2 * NPIX;
    const size_t yt_e  = (size_t)BS * NPIX * C2;
    const size_t wab_e = (size_t)WAO * CIN;
    const size_t wob_e = (size_t)CIN * C2;

    ushort *qt, *kt, *vb, *yt, *wab, *wob;
    if (ws_size >= (qt_e + kt_e + vb_e + yt_e + wab_e + wob_e) * sizeof(ushort)) {
        qt  = (ushort*)d_ws;
        kt  = qt + qt_e;
        vb  = kt + kt_e;
        yt  = vb + vb_e;
        wab = yt + yt_e;
        wob = wab + wab_e;
    } else {
        vb  = (ushort*)d_out;
        qt  = (ushort*)d_ws;
        kt  = qt + qt_e;
        yt  = kt + kt_e;
        wab = yt + yt_e;
        wob = wab + wab_e;
    }

    k_cvt_w <<<dim3(320),      256, 0, stream>>>(Wa, Wo, wab, wob);
    k_proj_a<<<dim3(64, 3, 8), 256, 0, stream>>>(inputs, wab, qt, kt, vb);
    k_attn  <<<dim3(512),      256, 0, stream>>>(qt, kt, vb, yt);
    k_proj_o<<<dim3(64, 4, 8), 256, 0, stream>>>(yt, wob, inputs, gamma, out);
}